// Round 6
// baseline (4102.153 us; speedup 1.0000x reference)
//
#include <hip/hip_runtime.h>
#include <hip/hip_bf16.h>

#define BATCH 64
#define SEQT  2048
#define FEAT  64
#define HID   128
#define G4    512   // 4*HID

// ---------- math helpers ----------
__device__ __forceinline__ float sigmoidf_(float x) {
    return 1.0f / (1.0f + __expf(-x));
}
__device__ __forceinline__ float seluf_(float x) {
    const float a = 1.6732632423543772f;
    const float s = 1.0507009873554805f;
    return x > 0.0f ? s * x : s * a * (__expf(x) - 1.0f);
}

// DPP quad-reduction: ctrl must be an immediate -> template parameter.
template <int CTRL>
__device__ __forceinline__ float dppadd_(float a) {
    int t = __builtin_amdgcn_update_dpp(0, __float_as_int(a), CTRL, 0xF, 0xF, false);
    return a + __int_as_float(t);
}
__device__ __forceinline__ float quad_sum_(float a) {
    a = dppadd_<0xB1>(a);   // quad_perm [1,0,3,2]
    a = dppadd_<0x4E>(a);   // quad_perm [2,3,0,1]
    return a;
}

// ---------- typed helpers for the xz buffer (fp32 or bf16) ----------
__device__ __forceinline__ float4 load4(const float* p) { return *(const float4*)p; }
__device__ __forceinline__ float4 load4(const __hip_bfloat16* p) {
    __hip_bfloat162 v0 = ((const __hip_bfloat162*)p)[0];
    __hip_bfloat162 v1 = ((const __hip_bfloat162*)p)[1];
    return make_float4(__low2float(v0), __high2float(v0),
                       __low2float(v1), __high2float(v1));
}
__device__ __forceinline__ void store4(float* p, float a, float b, float c, float d) {
    *(float4*)p = make_float4(a, b, c, d);
}
__device__ __forceinline__ void store4(__hip_bfloat16* p, float a, float b, float c, float d) {
    ((__hip_bfloat162*)p)[0] = __hip_bfloat162(__float2bfloat16(a), __float2bfloat16(b));
    ((__hip_bfloat162*)p)[1] = __hip_bfloat162(__float2bfloat16(c), __float2bfloat16(d));
}

// ---------- input-projection GEMM with gate-interleaved output ----------
// out[row*512 + l*4 + g] = bias[g*128+l] + sum_k X[row][k] * W[k][g*128+l]
template <typename OT>
__global__ __launch_bounds__(256) void gemm_xw_bias(
        const float* __restrict__ X, const float* __restrict__ W,
        const float* __restrict__ bias, OT* __restrict__ out, int K) {
    __shared__ float Ws[64 * 128];   // [k][g*32 + i]
    __shared__ float Xs[32 * 64];    // [r][k]
    const int tid = threadIdx.x;
    const int r0  = blockIdx.x * 32;
    const int l0  = blockIdx.y * 32;
    const int tx  = tid & 31;
    const int ty  = tid >> 5;

    float acc[4][4];
#pragma unroll
    for (int g = 0; g < 4; ++g) {
        float bv = bias[g * 128 + l0 + tx];
#pragma unroll
        for (int i = 0; i < 4; ++i) acc[i][g] = bv;
    }

    const int nkc = K >> 6;
    for (int kc = 0; kc < nkc; ++kc) {
        for (int idx = tid; idx < 64 * 128; idx += 256) {
            int k = idx >> 7, jj = idx & 127;
            int g = jj >> 5, i = jj & 31;
            Ws[idx] = W[(size_t)(kc * 64 + k) * G4 + g * 128 + l0 + i];
        }
        for (int idx = tid; idx < 32 * 64; idx += 256) {
            int r = idx >> 6, k = idx & 63;
            Xs[idx] = X[(size_t)(r0 + r) * K + kc * 64 + k];
        }
        __syncthreads();
#pragma unroll 4
        for (int k = 0; k < 64; ++k) {
            float wg0 = Ws[k * 128 +  0 + tx];
            float wg1 = Ws[k * 128 + 32 + tx];
            float wg2 = Ws[k * 128 + 64 + tx];
            float wg3 = Ws[k * 128 + 96 + tx];
#pragma unroll
            for (int i = 0; i < 4; ++i) {
                float xv = Xs[(ty * 4 + i) * 64 + k];
                acc[i][0] += xv * wg0; acc[i][1] += xv * wg1;
                acc[i][2] += xv * wg2; acc[i][3] += xv * wg3;
            }
        }
        __syncthreads();
    }
#pragma unroll
    for (int i = 0; i < 4; ++i) {
        store4(&out[(size_t)(r0 + ty * 4 + i) * G4 + (l0 + tx) * 4],
               acc[i][0], acc[i][1], acc[i][2], acc[i][3]);
    }
}

// ---------- recurrent LSTM layer (config V2-quad) ----------
// 512 threads = 8 waves per block, one block per batch row.
// lane: jp = lane>>3 (j-pair within wave), ko = lane&7 (K-eighth, 16 values).
// p = wave*8+jp in [0,64); thread owns cols {2p, 2p+1} x 4 gates over K [ko*16,ko*16+16).
// U slice = 32 named float4, PINNED in VGPRs via empty asm (blocks load remat).
// h broadcast: swizzled hsh (stride 20/16-group) -> conflict-free b128 broadcast.
// Partial reduce: DPP quad-sum (VALU) -> 2 half-sums -> one LDS exchange -> 2 gate waves.

#define UD(j2,g) float4 u##j2##g##_0, u##j2##g##_1, u##j2##g##_2, u##j2##g##_3;
#define ULD(j2,g,q) u##j2##g##_##q = make_float4( \
    Ub[(size_t)(4*q+0)*G4 + j2 + 128*g], Ub[(size_t)(4*q+1)*G4 + j2 + 128*g], \
    Ub[(size_t)(4*q+2)*G4 + j2 + 128*g], Ub[(size_t)(4*q+3)*G4 + j2 + 128*g]);
#define ULDALL(j2,g) ULD(j2,g,0) ULD(j2,g,1) ULD(j2,g,2) ULD(j2,g,3)
#define UPIN1(j2,g,q) asm volatile("" : "+v"(u##j2##g##_##q.x), "+v"(u##j2##g##_##q.y), \
                                        "+v"(u##j2##g##_##q.z), "+v"(u##j2##g##_##q.w));
#define UPIN(j2,g) UPIN1(j2,g,0) UPIN1(j2,g,1) UPIN1(j2,g,2) UPIN1(j2,g,3)
#define FMAQ(j2,g,q) \
    a##j2##g = fmaf(hb##q.x, u##j2##g##_##q.x, a##j2##g); \
    a##j2##g = fmaf(hb##q.y, u##j2##g##_##q.y, a##j2##g); \
    a##j2##g = fmaf(hb##q.z, u##j2##g##_##q.z, a##j2##g); \
    a##j2##g = fmaf(hb##q.w, u##j2##g##_##q.w, a##j2##g);
#define FMAALL(j2,g) FMAQ(j2,g,0) FMAQ(j2,g,1) FMAQ(j2,g,2) FMAQ(j2,g,3)

template <typename XT>
__global__ __launch_bounds__(512, 2) void lstm_rec(
        const XT* __restrict__ xz,      // [B][T][128][4] gate-interleaved
        const float* __restrict__ U,    // [128][512] row-major
        float* __restrict__ hout) {     // [B][T][128]
    const int b    = blockIdx.x;
    const int tid  = threadIdx.x;
    const int w    = tid >> 6;
    const int lane = tid & 63;
    const int jp   = lane >> 3;
    const int ko   = lane & 7;
    const int p    = w * 8 + jp;        // j-pair index, j0 = 2p
    const int j0   = 2 * p;

    __shared__ __align__(16) float part[2][64][12];  // [half][p][8 used, 12 stride]
    __shared__ __align__(16) float hsh[2][164];      // swizzled: k -> k + 4*(k>>4)

    // ---- stage U slice (2 j x 4 gates x 16 k = 128 floats) and PIN in VGPRs ----
    UD(0,0) UD(0,1) UD(0,2) UD(0,3) UD(1,0) UD(1,1) UD(1,2) UD(1,3)
    {
        const float* Ub = U + (size_t)(ko * 16) * G4 + j0;
        ULDALL(0,0) ULDALL(0,1) ULDALL(0,2) ULDALL(0,3)
        ULDALL(1,0) ULDALL(1,1) ULDALL(1,2) ULDALL(1,3)
    }
    UPIN(0,0) UPIN(0,1) UPIN(0,2) UPIN(0,3)
    UPIN(1,0) UPIN(1,1) UPIN(1,2) UPIN(1,3)

    float c = 0.0f;                      // cell state (gate threads tid<128)
    float4 hb0, hb1, hb2, hb3;           // my 16 h values (h(t-1))
    hb0 = hb1 = hb2 = hb3 = make_float4(0.f, 0.f, 0.f, 0.f);

    const XT* xrow = xz + (size_t)b * SEQT * G4 + tid * 4;   // gate thread j = tid
    float* hout_b  = hout + (size_t)b * SEQT * HID + tid;

    float4 xzv = make_float4(0.f, 0.f, 0.f, 0.f);
    if (tid < HID) xzv = load4(xrow);    // xz[t=0]

#pragma unroll 1
    for (int t = 0; t < SEQT; ++t) {
        // prefetch next xz early (a full step of latency cover)
        float4 nxz = xzv;
        if (tid < HID) {
            int tn = (t + 1 < SEQT) ? (t + 1) : t;
            nxz = load4(xrow + (size_t)tn * G4);
        }

        // ---- FMA phase: 8 accumulators (2 j x 4 gates) over my 16 k ----
        float a00 = 0.f, a01 = 0.f, a02 = 0.f, a03 = 0.f;
        float a10 = 0.f, a11 = 0.f, a12 = 0.f, a13 = 0.f;
        FMAALL(0,0) FMAALL(0,1) FMAALL(0,2) FMAALL(0,3)
        FMAALL(1,0) FMAALL(1,1) FMAALL(1,2) FMAALL(1,3)

        // ---- DPP quad pre-reduce: quad = 4 consecutive ko -> quad sums ----
        a00 = quad_sum_(a00); a01 = quad_sum_(a01); a02 = quad_sum_(a02); a03 = quad_sum_(a03);
        a10 = quad_sum_(a10); a11 = quad_sum_(a11); a12 = quad_sum_(a12); a13 = quad_sum_(a13);

        // lanes ko==0 and ko==4 hold the two half-sums; exchange via LDS
        if ((ko & 3) == 0) {
            float* pp = &part[ko >> 2][p][0];
            *(float4*)pp       = make_float4(a00, a01, a02, a03);
            *(float4*)(pp + 4) = make_float4(a10, a11, a12, a13);
        }
        __syncthreads();

        // ---- gate phase on waves 0,1 (thread j = tid) ----
        if (tid < HID) {
            const int gp = tid >> 1, ge = (tid & 1) * 4;
            float4 s0 = *(const float4*)&part[0][gp][ge];
            float4 s1 = *(const float4*)&part[1][gp][ge];
            float zi = s0.x + s1.x + xzv.x;
            float zf = s0.y + s1.y + xzv.y;
            float zg = s0.z + s1.z + xzv.z;
            float zo = s0.w + s1.w + xzv.w;
            float ig = sigmoidf_(zi);
            float fg = sigmoidf_(zf);
            float gg = seluf_(zg);
            float og = sigmoidf_(zo);
            c = fg * c + ig * gg;
            float h = og * seluf_(c);
            hsh[(t + 1) & 1][tid + 4 * (tid >> 4)] = h;   // swizzled store
            hout_b[(size_t)t * HID] = h;
        }
        __syncthreads();

        // ---- reload my 16 h values (conflict-free 8-way-broadcast b128 reads) ----
        {
            const float* hbase = &hsh[(t + 1) & 1][ko * 20];
            hb0 = *(const float4*)(hbase);
            hb1 = *(const float4*)(hbase + 4);
            hb2 = *(const float4*)(hbase + 8);
            hb3 = *(const float4*)(hbase + 12);
        }
        xzv = nxz;
    }
}

// ---------- host launch ----------
// Workspace holds ONLY the xz buffer; layer-1 h lives in d_out (overwritten by
// layer 2 afterwards — harness validates final state only).
extern "C" void kernel_launch(void* const* d_in, const int* in_sizes, int n_in,
                              void* d_out, int out_size, void* d_ws, size_t ws_size,
                              hipStream_t stream) {
    const float* x  = (const float*)d_in[0];
    const float* W1 = (const float*)d_in[1];
    const float* U1 = (const float*)d_in[2];
    const float* b1 = (const float*)d_in[3];
    const float* W2 = (const float*)d_in[4];
    const float* U2 = (const float*)d_in[5];
    const float* b2 = (const float*)d_in[6];
    float* out = (float*)d_out;

    const size_t BT = (size_t)BATCH * SEQT;
    const size_t xz_f32_bytes = BT * G4 * sizeof(float);   // 256 MB

    dim3 ggrid((unsigned)(BT / 32), 4), gblk(256);
    dim3 rgrid(BATCH), rblk(512);

    float* h1 = out;   // reuse output buffer for layer-1 sequence

    if (ws_size >= xz_f32_bytes) {
        float* xzbuf = (float*)d_ws;
        gemm_xw_bias<float><<<ggrid, gblk, 0, stream>>>(x, W1, b1, xzbuf, FEAT);
        lstm_rec<float><<<rgrid, rblk, 0, stream>>>(xzbuf, U1, h1);
        gemm_xw_bias<float><<<ggrid, gblk, 0, stream>>>(h1, W2, b2, xzbuf, HID);
        lstm_rec<float><<<rgrid, rblk, 0, stream>>>(xzbuf, U2, out);
    } else {
        __hip_bfloat16* xzbuf = (__hip_bfloat16*)d_ws;
        gemm_xw_bias<__hip_bfloat16><<<ggrid, gblk, 0, stream>>>(x, W1, b1, xzbuf, FEAT);
        lstm_rec<__hip_bfloat16><<<rgrid, rblk, 0, stream>>>(xzbuf, U1, h1);
        gemm_xw_bias<__hip_bfloat16><<<ggrid, gblk, 0, stream>>>(h1, W2, b2, xzbuf, HID);
        lstm_rec<__hip_bfloat16><<<rgrid, rblk, 0, stream>>>(xzbuf, U2, out);
    }
}

// Round 7
// 3427.774 us; speedup vs baseline: 1.1967x; 1.1967x over previous
//
#include <hip/hip_runtime.h>
#include <hip/hip_bf16.h>

#define BATCH 64
#define SEQT  2048
#define FEAT  64
#define HID   128
#define G4    512   // 4*HID

using short8  = __attribute__((ext_vector_type(8))) short;   // 8 x bf16 (4 VGPRs)
using floatx4 = __attribute__((ext_vector_type(4))) float;   // MFMA C/D

// ---------- math helpers ----------
__device__ __forceinline__ float sigmoidf_(float x) {
    return __builtin_amdgcn_rcpf(1.0f + __expf(-x));
}
__device__ __forceinline__ float seluf_(float x) {
    const float a = 1.6732632423543772f;
    const float s = 1.0507009873554805f;
    return x > 0.0f ? s * x : s * a * (__expf(x) - 1.0f);
}
// fp32 -> bf16 bits, round-to-nearest-even
__device__ __forceinline__ unsigned short f2bf_(float f) {
    unsigned u = __float_as_uint(f);
    u += 0x7FFFu + ((u >> 16) & 1u);
    return (unsigned short)(u >> 16);
}

// ---------- typed helpers for the xz buffer (fp32 or bf16) ----------
__device__ __forceinline__ float4 load4(const float* p) { return *(const float4*)p; }
__device__ __forceinline__ float4 load4(const __hip_bfloat16* p) {
    __hip_bfloat162 v0 = ((const __hip_bfloat162*)p)[0];
    __hip_bfloat162 v1 = ((const __hip_bfloat162*)p)[1];
    return make_float4(__low2float(v0), __high2float(v0),
                       __low2float(v1), __high2float(v1));
}
__device__ __forceinline__ void store4(float* p, float a, float b, float c, float d) {
    *(float4*)p = make_float4(a, b, c, d);
}
__device__ __forceinline__ void store4(__hip_bfloat16* p, float a, float b, float c, float d) {
    ((__hip_bfloat162*)p)[0] = __hip_bfloat162(__float2bfloat16(a), __float2bfloat16(b));
    ((__hip_bfloat162*)p)[1] = __hip_bfloat162(__float2bfloat16(c), __float2bfloat16(d));
}

// ---------- input-projection GEMM with gate-interleaved output ----------
// out[row*512 + j*4 + g] = bias[g*128+j] + sum_k X[row][k] * W[k][g*128+j]
template <typename OT>
__global__ __launch_bounds__(256) void gemm_xw_bias(
        const float* __restrict__ X, const float* __restrict__ W,
        const float* __restrict__ bias, OT* __restrict__ out, int K) {
    __shared__ float Ws[64 * 128];   // [k][g*32 + i]
    __shared__ float Xs[32 * 64];    // [r][k]
    const int tid = threadIdx.x;
    const int r0  = blockIdx.x * 32;
    const int l0  = blockIdx.y * 32;
    const int tx  = tid & 31;
    const int ty  = tid >> 5;

    float acc[4][4];
#pragma unroll
    for (int g = 0; g < 4; ++g) {
        float bv = bias[g * 128 + l0 + tx];
#pragma unroll
        for (int i = 0; i < 4; ++i) acc[i][g] = bv;
    }

    const int nkc = K >> 6;
    for (int kc = 0; kc < nkc; ++kc) {
        for (int idx = tid; idx < 64 * 128; idx += 256) {
            int k = idx >> 7, jj = idx & 127;
            int g = jj >> 5, i = jj & 31;
            Ws[idx] = W[(size_t)(kc * 64 + k) * G4 + g * 128 + l0 + i];
        }
        for (int idx = tid; idx < 32 * 64; idx += 256) {
            int r = idx >> 6, k = idx & 63;
            Xs[idx] = X[(size_t)(r0 + r) * K + kc * 64 + k];
        }
        __syncthreads();
#pragma unroll 4
        for (int k = 0; k < 64; ++k) {
            float wg0 = Ws[k * 128 +  0 + tx];
            float wg1 = Ws[k * 128 + 32 + tx];
            float wg2 = Ws[k * 128 + 64 + tx];
            float wg3 = Ws[k * 128 + 96 + tx];
#pragma unroll
            for (int i = 0; i < 4; ++i) {
                float xv = Xs[(ty * 4 + i) * 64 + k];
                acc[i][0] += xv * wg0; acc[i][1] += xv * wg1;
                acc[i][2] += xv * wg2; acc[i][3] += xv * wg3;
            }
        }
        __syncthreads();
    }
#pragma unroll
    for (int i = 0; i < 4; ++i) {
        store4(&out[(size_t)(r0 + ty * 4 + i) * G4 + (l0 + tx) * 4],
               acc[i][0], acc[i][1], acc[i][2], acc[i][3]);
    }
}

// ---------- recurrent LSTM layer (config M: MFMA broadcast-A) ----------
// One block (512 threads = 8 waves) per batch row.
// z[n] = sum_k h[k]*U[k][n] via mfma_f32_16x16x32_bf16:
//   A[m][k] = h[k] for ALL m (broadcast LDS reads) -> every D row = z.
//   B = U bf16, wave w holds N-tiles {w, w+8, w+16, w+24} -> 64 VGPRs, loop-invariant.
//   Thread gets (i,f,g,o) at j = w*16 + (lane&15): gate math thread-local,
//   replicated across the 4 quads (identical values; quad 0 writes results).
// hA ping-pong (2 x 128 bf16 = 512 B LDS) -> ONE barrier per step.
template <typename XT>
__global__ __launch_bounds__(512)
__attribute__((amdgpu_waves_per_eu(2, 2)))
void lstm_rec(const XT* __restrict__ xz,      // [B][T][128][4] gate-interleaved
              const float* __restrict__ U,    // [128][512] row-major fp32
              float* __restrict__ hout) {     // [B][T][128]
    const int b    = blockIdx.x;
    const int tid  = threadIdx.x;
    const int w    = tid >> 6;
    const int lane = tid & 63;
    const int c16  = lane & 15;
    const int quad = lane >> 4;
    const int j    = w * 16 + c16;            // h-column this thread owns

    __shared__ __align__(16) short hA[2][HID];   // bf16 h, ping-pong

    // ---- stage B fragments: bfrag[g][kc] = U[kc*32+quad*8+jj][g*128+j] (bf16) ----
    short8 bfrag[4][4];
#pragma unroll
    for (int g = 0; g < 4; ++g) {
        const float* Ucol = U + (size_t)(g * 128 + j);
#pragma unroll
        for (int kc = 0; kc < 4; ++kc) {
            short8 v;
#pragma unroll
            for (int jj = 0; jj < 8; ++jj) {
                int k = kc * 32 + quad * 8 + jj;
                v[jj] = (short)f2bf_(Ucol[(size_t)k * G4]);
            }
            bfrag[g][kc] = v;
        }
    }

    if (tid < HID) hA[0][tid] = 0;            // h(-1) = 0
    float cst = 0.0f;                          // cell state (replicated x4 quads)
    floatx4 zero4 = {0.f, 0.f, 0.f, 0.f};

    const XT* xrow = xz + (size_t)b * SEQT * G4 + j * 4;
    float* hout_b  = hout + (size_t)b * SEQT * HID + j;

    float4 xzv = load4(xrow);                  // xz[t=0] (all quads same addr)
    __syncthreads();

#pragma unroll 1
    for (int t = 0; t < SEQT; ++t) {
        // ---- A fragments: broadcast h(t-1); lane reads its quad's 8 k-values ----
        const short* hbuf = &hA[t & 1][0];
        short8 af[4];
#pragma unroll
        for (int kc = 0; kc < 4; ++kc)
            af[kc] = *(const short8*)&hbuf[kc * 32 + quad * 8];

        // prefetch next step's xz (consumed next iteration)
        int tn = (t + 1 < SEQT) ? t + 1 : t;
        float4 nxz = load4(xrow + (size_t)tn * G4);

        // ---- MFMA: 4 gate-tiles x 4 K-chunks ----
        floatx4 acc[4];
#pragma unroll
        for (int g = 0; g < 4; ++g)
            acc[g] = __builtin_amdgcn_mfma_f32_16x16x32_bf16(af[0], bfrag[g][0], zero4, 0, 0, 0);
#pragma unroll
        for (int kc = 1; kc < 4; ++kc)
#pragma unroll
            for (int g = 0; g < 4; ++g)
                acc[g] = __builtin_amdgcn_mfma_f32_16x16x32_bf16(af[kc], bfrag[g][kc], acc[g], 0, 0, 0);

        // ---- gates (all rows of D identical -> use reg 0) ----
        float zi = acc[0][0] + xzv.x;
        float zf = acc[1][0] + xzv.y;
        float zg = acc[2][0] + xzv.z;
        float zo = acc[3][0] + xzv.w;
        float ig = sigmoidf_(zi);
        float fg = sigmoidf_(zf);
        float gg = seluf_(zg);
        float og = sigmoidf_(zo);
        cst = fg * cst + ig * gg;
        float h = og * seluf_(cst);

        if (lane < 16) {                       // quad 0 publishes
            hA[(t + 1) & 1][j] = (short)f2bf_(h);
            hout_b[(size_t)t * HID] = h;
        }
        __syncthreads();                       // h(t) visible before next A-reads
        xzv = nxz;
    }
}

// ---------- host launch ----------
// Workspace holds ONLY the xz buffer; layer-1 h lives in d_out (overwritten by
// layer 2 afterwards — harness validates final state only).
extern "C" void kernel_launch(void* const* d_in, const int* in_sizes, int n_in,
                              void* d_out, int out_size, void* d_ws, size_t ws_size,
                              hipStream_t stream) {
    const float* x  = (const float*)d_in[0];
    const float* W1 = (const float*)d_in[1];
    const float* U1 = (const float*)d_in[2];
    const float* b1 = (const float*)d_in[3];
    const float* W2 = (const float*)d_in[4];
    const float* U2 = (const float*)d_in[5];
    const float* b2 = (const float*)d_in[6];
    float* out = (float*)d_out;

    const size_t BT = (size_t)BATCH * SEQT;
    const size_t xz_f32_bytes = BT * G4 * sizeof(float);   // 256 MB

    dim3 ggrid((unsigned)(BT / 32), 4), gblk(256);
    dim3 rgrid(BATCH), rblk(512);

    float* h1 = out;   // reuse output buffer for layer-1 sequence

    if (ws_size >= xz_f32_bytes) {
        float* xzbuf = (float*)d_ws;
        gemm_xw_bias<float><<<ggrid, gblk, 0, stream>>>(x, W1, b1, xzbuf, FEAT);
        lstm_rec<float><<<rgrid, rblk, 0, stream>>>(xzbuf, U1, h1);
        gemm_xw_bias<float><<<ggrid, gblk, 0, stream>>>(h1, W2, b2, xzbuf, HID);
        lstm_rec<float><<<rgrid, rblk, 0, stream>>>(xzbuf, U2, out);
    } else {
        __hip_bfloat16* xzbuf = (__hip_bfloat16*)d_ws;
        gemm_xw_bias<__hip_bfloat16><<<ggrid, gblk, 0, stream>>>(x, W1, b1, xzbuf, FEAT);
        lstm_rec<__hip_bfloat16><<<rgrid, rblk, 0, stream>>>(xzbuf, U1, h1);
        gemm_xw_bias<__hip_bfloat16><<<ggrid, gblk, 0, stream>>>(h1, W2, b2, xzbuf, HID);
        lstm_rec<__hip_bfloat16><<<rgrid, rblk, 0, stream>>>(xzbuf, U2, out);
    }
}

// Round 8
// 2666.299 us; speedup vs baseline: 1.5385x; 1.2856x over previous
//
#include <hip/hip_runtime.h>
#include <hip/hip_bf16.h>

#define BATCH 64
#define SEQT  2048
#define FEAT  64
#define HID   128
#define G4    512              // 4*HID
#define CHUNK 16
#define NCHUNK (SEQT / CHUNK)  // 128

using short8  = __attribute__((ext_vector_type(8))) short;   // 8 x bf16 (4 VGPRs)
using floatx4 = __attribute__((ext_vector_type(4))) float;   // MFMA C/D

// ---------- math helpers ----------
__device__ __forceinline__ float sigmoidf_(float x) {
    return __builtin_amdgcn_rcpf(1.0f + __expf(-x));
}
__device__ __forceinline__ float seluf_(float x) {
    const float a = 1.6732632423543772f;
    const float s = 1.0507009873554805f;
    return x > 0.0f ? s * x : s * a * (__expf(x) - 1.0f);
}
// fp32 -> bf16 bits, round-to-nearest-even
__device__ __forceinline__ unsigned short f2bf_(float f) {
    unsigned u = __float_as_uint(f);
    u += 0x7FFFu + ((u >> 16) & 1u);
    return (unsigned short)(u >> 16);
}
__device__ __forceinline__ float bf2f_(unsigned short s) {
    return __uint_as_float((unsigned)s << 16);
}

// ---------- input-projection GEMM, gate-interleaved bf16 output ----------
// out[row*512 + j*4 + g] = bias[g*128+j] + sum_k X[row][k] * W[k][g*128+j]
__global__ __launch_bounds__(256) void gemm_xw_bias(
        const float* __restrict__ X, const float* __restrict__ W,
        const float* __restrict__ bias, __hip_bfloat16* __restrict__ out, int K) {
    __shared__ float Ws[64 * 128];   // [k][g*32 + i]
    __shared__ float Xs[32 * 64];    // [r][k]
    const int tid = threadIdx.x;
    const int r0  = blockIdx.x * 32;
    const int l0  = blockIdx.y * 32;
    const int tx  = tid & 31;
    const int ty  = tid >> 5;

    float acc[4][4];
#pragma unroll
    for (int g = 0; g < 4; ++g) {
        float bv = bias[g * 128 + l0 + tx];
#pragma unroll
        for (int i = 0; i < 4; ++i) acc[i][g] = bv;
    }

    const int nkc = K >> 6;
    for (int kc = 0; kc < nkc; ++kc) {
        for (int idx = tid; idx < 64 * 128; idx += 256) {
            int k = idx >> 7, jj = idx & 127;
            int g = jj >> 5, i = jj & 31;
            Ws[idx] = W[(size_t)(kc * 64 + k) * G4 + g * 128 + l0 + i];
        }
        for (int idx = tid; idx < 32 * 64; idx += 256) {
            int r = idx >> 6, k = idx & 63;
            Xs[idx] = X[(size_t)(r0 + r) * K + kc * 64 + k];
        }
        __syncthreads();
#pragma unroll 4
        for (int k = 0; k < 64; ++k) {
            float wg0 = Ws[k * 128 +  0 + tx];
            float wg1 = Ws[k * 128 + 32 + tx];
            float wg2 = Ws[k * 128 + 64 + tx];
            float wg3 = Ws[k * 128 + 96 + tx];
#pragma unroll
            for (int i = 0; i < 4; ++i) {
                float xv = Xs[(ty * 4 + i) * 64 + k];
                acc[i][0] += xv * wg0; acc[i][1] += xv * wg1;
                acc[i][2] += xv * wg2; acc[i][3] += xv * wg3;
            }
        }
        __syncthreads();
    }
#pragma unroll
    for (int i = 0; i < 4; ++i) {
        __hip_bfloat16* p = &out[(size_t)(r0 + ty * 4 + i) * G4 + (l0 + tx) * 4];
        ((__hip_bfloat162*)p)[0] = __hip_bfloat162(__float2bfloat16(acc[i][0]),
                                                   __float2bfloat16(acc[i][1]));
        ((__hip_bfloat162*)p)[1] = __hip_bfloat162(__float2bfloat16(acc[i][2]),
                                                   __float2bfloat16(acc[i][3]));
    }
}

// ---------- recurrent LSTM layer (config M2: MFMA broadcast-A + chunked I/O) ----------
// One block (512 threads = 8 waves) per batch row.
// Per-step global traffic REMOVED: xz staged 16 steps at a time into double-
// buffered LDS (reg prefetch at chunk top, ds_write at chunk end); h output
// buffered in LDS and flushed once per chunk. The per-step __syncthreads thus
// drains no long-latency vmem ops except twice per 16 steps.
__global__ __launch_bounds__(512)
__attribute__((amdgpu_waves_per_eu(2, 2)))
void lstm_rec(const __hip_bfloat16* __restrict__ xz,  // [B][T][128][4] bf16
              const float* __restrict__ U,            // [128][512] fp32
              float* __restrict__ hout) {             // [B][T][128]
    const int b    = blockIdx.x;
    const int tid  = threadIdx.x;
    const int w    = tid >> 6;
    const int lane = tid & 63;
    const int c16  = lane & 15;
    const int quad = lane >> 4;
    const int j    = w * 16 + c16;            // output column this thread owns

    __shared__ __align__(16) short hA[2][HID];            // bf16 h ping-pong
    __shared__ __align__(16) short xzbuf[2][CHUNK * G4];  // 2 x 16 KB bf16
    __shared__ __align__(16) float hbuf[CHUNK * HID];     // 8 KB fp32

    // ---- stage B fragments: bfrag[g][kc] = U[kc*32+quad*8+jj][g*128+j] (bf16) ----
    short8 bfrag[4][4];
#pragma unroll
    for (int g = 0; g < 4; ++g) {
        const float* Ucol = U + (size_t)(g * 128 + j);
#pragma unroll
        for (int kc = 0; kc < 4; ++kc) {
            short8 v;
#pragma unroll
            for (int jj = 0; jj < 8; ++jj) {
                int k = kc * 32 + quad * 8 + jj;
                v[jj] = (short)f2bf_(Ucol[(size_t)k * G4]);
            }
            bfrag[g][kc] = v;
        }
    }

    const char* xzbase = (const char*)(xz + (size_t)b * SEQT * G4);
    // ---- preload chunk 0 into xzbuf[0] ----
    {
        const uint4* src = (const uint4*)xzbase;
        uint4 a0 = src[tid * 2], a1 = src[tid * 2 + 1];
        uint4* dst = (uint4*)&xzbuf[0][0];
        dst[tid * 2] = a0; dst[tid * 2 + 1] = a1;
    }
    if (tid < HID) hA[0][tid] = 0;            // h(-1) = 0
    float cst = 0.0f;                          // cell state (replicated x4 quads)
    floatx4 zero4 = {0.f, 0.f, 0.f, 0.f};
    __syncthreads();

    float* hout_c = hout + (size_t)b * SEQT * HID;

    for (int c = 0; c < NCHUNK; ++c) {
        // issue prefetch of chunk c+1 (in flight across the whole chunk)
        uint4 pf0, pf1;
        if (c + 1 < NCHUNK) {
            const uint4* src = (const uint4*)(xzbase + (size_t)(c + 1) * CHUNK * G4 * 2);
            pf0 = src[tid * 2];
            pf1 = src[tid * 2 + 1];
        }
        const short* xzc = &xzbuf[c & 1][0];

#pragma unroll 2
        for (int s = 0; s < CHUNK; ++s) {
            // ---- A fragments: broadcast h(t-1) ----
            const short* hb = &hA[s & 1][0];
            short8 af[4];
#pragma unroll
            for (int kc = 0; kc < 4; ++kc)
                af[kc] = *(const short8*)&hb[kc * 32 + quad * 8];

            // ---- xz for this step from LDS (bf16 x4 -> fp32) ----
            ushort4 xq = *(const ushort4*)&xzc[s * G4 + j * 4];

            // ---- MFMA: 4 gate-tiles x 4 K-chunks ----
            floatx4 acc[4];
#pragma unroll
            for (int g = 0; g < 4; ++g)
                acc[g] = __builtin_amdgcn_mfma_f32_16x16x32_bf16(af[0], bfrag[g][0], zero4, 0, 0, 0);
#pragma unroll
            for (int kc = 1; kc < 4; ++kc)
#pragma unroll
                for (int g = 0; g < 4; ++g)
                    acc[g] = __builtin_amdgcn_mfma_f32_16x16x32_bf16(af[kc], bfrag[g][kc], acc[g], 0, 0, 0);

            // ---- gates (all D rows identical -> reg 0) ----
            float zi = acc[0][0] + bf2f_(xq.x);
            float zf = acc[1][0] + bf2f_(xq.y);
            float zg = acc[2][0] + bf2f_(xq.z);
            float zo = acc[3][0] + bf2f_(xq.w);
            float ig = sigmoidf_(zi);
            float fg = sigmoidf_(zf);
            float gg = seluf_(zg);
            float og = sigmoidf_(zo);
            cst = fg * cst + ig * gg;
            float h = og * seluf_(cst);

            if (lane < 16) {                   // quad 0 publishes
                hA[(s + 1) & 1][j] = (short)f2bf_(h);
                hbuf[s * HID + j]  = h;
            }
            __syncthreads();                   // h(t) + hbuf visible
        }

        // ---- chunk boundary: flush hbuf, install prefetched xz chunk ----
        {
            float4 hv = *(const float4*)&hbuf[tid * 4];
            *(float4*)&hout_c[((size_t)c * CHUNK) * HID + tid * 4] = hv;
            if (c + 1 < NCHUNK) {
                uint4* dst = (uint4*)&xzbuf[(c + 1) & 1][0];
                dst[tid * 2] = pf0;
                dst[tid * 2 + 1] = pf1;
            }
        }
        __syncthreads();                       // xzbuf/hbuf safe for next chunk
    }
}

// ---------- host launch ----------
// d_ws holds the bf16 xz buffer (128 MB — proven to fit in prior rounds).
// Layer-1 h sequence lives in d_out (overwritten by layer 2; only final
// state is validated, and every call does identical work).
extern "C" void kernel_launch(void* const* d_in, const int* in_sizes, int n_in,
                              void* d_out, int out_size, void* d_ws, size_t ws_size,
                              hipStream_t stream) {
    const float* x  = (const float*)d_in[0];
    const float* W1 = (const float*)d_in[1];
    const float* U1 = (const float*)d_in[2];
    const float* b1 = (const float*)d_in[3];
    const float* W2 = (const float*)d_in[4];
    const float* U2 = (const float*)d_in[5];
    const float* b2 = (const float*)d_in[6];
    float* out = (float*)d_out;

    const size_t BT = (size_t)BATCH * SEQT;
    __hip_bfloat16* xzbuf = (__hip_bfloat16*)d_ws;   // 128 MB bf16
    float* h1 = out;   // reuse output buffer for layer-1 sequence

    dim3 ggrid((unsigned)(BT / 32), 4), gblk(256);
    dim3 rgrid(BATCH), rblk(512);

    gemm_xw_bias<<<ggrid, gblk, 0, stream>>>(x, W1, b1, xzbuf, FEAT);
    lstm_rec<<<rgrid, rblk, 0, stream>>>(xzbuf, U1, h1);
    gemm_xw_bias<<<ggrid, gblk, 0, stream>>>(h1, W2, b2, xzbuf, HID);
    lstm_rec<<<rgrid, rblk, 0, stream>>>(xzbuf, U2, out);
}

// Round 9
// 1499.335 us; speedup vs baseline: 2.7360x; 1.7783x over previous
//
#include <hip/hip_runtime.h>
#include <hip/hip_bf16.h>

#define BATCH 64
#define SEQT  2048
#define FEAT  64
#define HID   128
#define G4    512              // 4*HID
#define CHUNK 16
#define NCHUNK (SEQT / CHUNK)  // 128

using short8  = __attribute__((ext_vector_type(8))) short;   // 8 x bf16 (4 VGPRs)
using floatx4 = __attribute__((ext_vector_type(4))) float;   // MFMA C/D

// ---------- math helpers ----------
__device__ __forceinline__ float sigmoidf_(float x) {
    return __builtin_amdgcn_rcpf(1.0f + __expf(-x));
}
__device__ __forceinline__ float seluf_(float x) {
    const float a = 1.6732632423543772f;
    const float s = 1.0507009873554805f;
    return x > 0.0f ? s * x : s * a * (__expf(x) - 1.0f);
}
// fp32 -> bf16 bits, round-to-nearest-even
__device__ __forceinline__ unsigned short f2bf_(float f) {
    unsigned u = __float_as_uint(f);
    u += 0x7FFFu + ((u >> 16) & 1u);
    return (unsigned short)(u >> 16);
}
__device__ __forceinline__ float bf2f_(unsigned short s) {
    return __uint_as_float((unsigned)s << 16);
}

// ---------- input-projection GEMM (layer 1 only), gate-interleaved bf16 out ----------
// out[row*512 + j*4 + g] = bias[g*128+j] + sum_k X[row][k] * W[k][g*128+j]
__global__ __launch_bounds__(256) void gemm_xw_bias(
        const float* __restrict__ X, const float* __restrict__ W,
        const float* __restrict__ bias, __hip_bfloat16* __restrict__ out, int K) {
    __shared__ float Ws[64 * 128];   // [k][g*32 + i]
    __shared__ float Xs[32 * 64];    // [r][k]
    const int tid = threadIdx.x;
    const int r0  = blockIdx.x * 32;
    const int l0  = blockIdx.y * 32;
    const int tx  = tid & 31;
    const int ty  = tid >> 5;

    float acc[4][4];
#pragma unroll
    for (int g = 0; g < 4; ++g) {
        float bv = bias[g * 128 + l0 + tx];
#pragma unroll
        for (int i = 0; i < 4; ++i) acc[i][g] = bv;
    }

    const int nkc = K >> 6;
    for (int kc = 0; kc < nkc; ++kc) {
        for (int idx = tid; idx < 64 * 128; idx += 256) {
            int k = idx >> 7, jj = idx & 127;
            int g = jj >> 5, i = jj & 31;
            Ws[idx] = W[(size_t)(kc * 64 + k) * G4 + g * 128 + l0 + i];
        }
        for (int idx = tid; idx < 32 * 64; idx += 256) {
            int r = idx >> 6, k = idx & 63;
            Xs[idx] = X[(size_t)(r0 + r) * K + kc * 64 + k];
        }
        __syncthreads();
#pragma unroll 4
        for (int k = 0; k < 64; ++k) {
            float wg0 = Ws[k * 128 +  0 + tx];
            float wg1 = Ws[k * 128 + 32 + tx];
            float wg2 = Ws[k * 128 + 64 + tx];
            float wg3 = Ws[k * 128 + 96 + tx];
#pragma unroll
            for (int i = 0; i < 4; ++i) {
                float xv = Xs[(ty * 4 + i) * 64 + k];
                acc[i][0] += xv * wg0; acc[i][1] += xv * wg1;
                acc[i][2] += xv * wg2; acc[i][3] += xv * wg3;
            }
        }
        __syncthreads();
    }
#pragma unroll
    for (int i = 0; i < 4; ++i) {
        __hip_bfloat16* p = &out[(size_t)(r0 + ty * 4 + i) * G4 + (l0 + tx) * 4];
        ((__hip_bfloat162*)p)[0] = __hip_bfloat162(__float2bfloat16(acc[i][0]),
                                                   __float2bfloat16(acc[i][1]));
        ((__hip_bfloat162*)p)[1] = __hip_bfloat162(__float2bfloat16(acc[i][2]),
                                                   __float2bfloat16(acc[i][3]));
    }
}

// ---------- fused two-layer LSTM, wavefront-pipelined ----------
// 128 blocks x 512 threads, all co-resident (<= 256 CUs -> no deadlock).
// Blocks [0,64):   layer 1, row b. Rec over xz1 (ws); publishes bf16 h1 chunk +
//                  flag (release/agent; barrier's vmcnt(0) drain orders stores).
// Blocks [64,128): layer 2, row b. Spins (acquire/agent) on flag, stages h1
//                  chunk, computes xz2 = h1c @ W2 + b2 via MFMA (M=16 timesteps),
//                  then runs 16 rec steps; writes fp32 h2 to out.
__global__ __launch_bounds__(512)
__attribute__((amdgpu_waves_per_eu(2, 2)))
void fused_lstm(const __hip_bfloat16* __restrict__ xz1,  // [B][T][512] bf16 (ws)
                const float* __restrict__ U1,            // [128][512] fp32
                const float* __restrict__ U2,
                const float* __restrict__ W2,            // [128][512] fp32
                const float* __restrict__ b2,            // [512]
                __hip_bfloat16* __restrict__ h1g,        // [B][T][128] bf16 (ws)
                unsigned* __restrict__ flags,            // [B] (zeroed by memset)
                float* __restrict__ out) {               // [B][T][128] fp32
    const bool l2  = blockIdx.x >= BATCH;
    const int  b   = l2 ? ((int)blockIdx.x - BATCH) : (int)blockIdx.x;
    const int tid  = threadIdx.x;
    const int w    = tid >> 6;
    const int lane = tid & 63;
    const int c16  = lane & 15;
    const int quad = lane >> 4;
    const int j    = w * 16 + c16;            // output column this thread owns

    __shared__ __align__(16) short hA[2][HID];            // bf16 h ping-pong
    __shared__ __align__(16) short xzbuf[2][CHUNK * G4];  // 2 x 16 KB bf16
    __shared__ __align__(16) float hbuf[CHUNK * HID];     // 8 KB fp32
    __shared__ __align__(16) short h1c[CHUNK * HID];      // 4 KB bf16 (l2 only)

    // ---- stage U fragments (recurrent weights) ----
    const float* U = l2 ? U2 : U1;
    short8 bfrag[4][4];
#pragma unroll
    for (int g = 0; g < 4; ++g) {
        const float* Ucol = U + (size_t)(g * 128 + j);
#pragma unroll
        for (int kc = 0; kc < 4; ++kc) {
            short8 v;
#pragma unroll
            for (int jj = 0; jj < 8; ++jj) {
                int k = kc * 32 + quad * 8 + jj;
                v[jj] = (short)f2bf_(Ucol[(size_t)k * G4]);
            }
            bfrag[g][kc] = v;
        }
    }

    // ---- layer-2 blocks also stage W2 fragments + gate-interleaved bias ----
    short8 w2frag[4][4];
    float4 bias4 = make_float4(0.f, 0.f, 0.f, 0.f);
    if (l2) {
#pragma unroll
        for (int g = 0; g < 4; ++g) {
            const float* Wcol = W2 + (size_t)(g * 128 + j);
#pragma unroll
            for (int kc = 0; kc < 4; ++kc) {
                short8 v;
#pragma unroll
                for (int jj = 0; jj < 8; ++jj) {
                    int k = kc * 32 + quad * 8 + jj;
                    v[jj] = (short)f2bf_(Wcol[(size_t)k * G4]);
                }
                w2frag[g][kc] = v;
            }
        }
        bias4 = make_float4(b2[j], b2[128 + j], b2[256 + j], b2[384 + j]);
    }

    const char* xzbase = (const char*)xz1 + (size_t)b * SEQT * G4 * 2;
    if (!l2) {   // preload chunk 0 (consecutive-lane b128: no LDS bank conflicts)
        const uint4* src = (const uint4*)xzbase;
        uint4 a0 = src[tid], a1 = src[tid + 512];
        uint4* dst = (uint4*)&xzbuf[0][0];
        dst[tid] = a0; dst[tid + 512] = a1;
    }
    if (tid < HID) hA[0][tid] = 0;            // h(-1) = 0
    float cst = 0.0f;                          // cell state (replicated x4 quads)
    floatx4 zero4 = {0.f, 0.f, 0.f, 0.f};
    __syncthreads();

    float*          out_b = out + (size_t)b * SEQT * HID;
    __hip_bfloat16* h1_b  = h1g + (size_t)b * SEQT * HID;

    for (int c = 0; c < NCHUNK; ++c) {
        uint4 pf0, pf1;
        if (!l2) {
            // prefetch next xz1 chunk (in flight across the whole chunk)
            if (c + 1 < NCHUNK) {
                const uint4* src = (const uint4*)(xzbase + (size_t)(c + 1) * CHUNK * G4 * 2);
                pf0 = src[tid];
                pf1 = src[tid + 512];
            }
        } else {
            // ---- wait for layer-1 chunk c, then build xz2 chunk in LDS ----
            if (tid == 0) {
                while (__hip_atomic_load(&flags[b], __ATOMIC_ACQUIRE,
                                         __HIP_MEMORY_SCOPE_AGENT) < (unsigned)(c + 1))
                    __builtin_amdgcn_s_sleep(8);
            }
            __syncthreads();
            const ushort4* hsrc =
                (const ushort4*)((const char*)h1_b + (size_t)c * CHUNK * HID * 2);
            ((ushort4*)h1c)[tid] = hsrc[tid];
            __syncthreads();

            // xz2[t][n] = sum_k h1c[t][k] * W2[k][n] + b2  (M=16 timesteps)
            short8 af2[4];
#pragma unroll
            for (int kc = 0; kc < 4; ++kc)
                af2[kc] = *(const short8*)&h1c[c16 * HID + kc * 32 + quad * 8];
            floatx4 acc2[4];
#pragma unroll
            for (int g = 0; g < 4; ++g)
                acc2[g] = __builtin_amdgcn_mfma_f32_16x16x32_bf16(af2[0], w2frag[g][0], zero4, 0, 0, 0);
#pragma unroll
            for (int kc = 1; kc < 4; ++kc)
#pragma unroll
                for (int g = 0; g < 4; ++g)
                    acc2[g] = __builtin_amdgcn_mfma_f32_16x16x32_bf16(af2[kc], w2frag[g][kc], acc2[g], 0, 0, 0);
            // D mapping: col=lane&15 (our j), row=quad*4+reg (timestep)
#pragma unroll
            for (int r = 0; r < 4; ++r) {
                int s = quad * 4 + r;
                ushort4 xw = make_ushort4(f2bf_(acc2[0][r] + bias4.x),
                                          f2bf_(acc2[1][r] + bias4.y),
                                          f2bf_(acc2[2][r] + bias4.z),
                                          f2bf_(acc2[3][r] + bias4.w));
                *(ushort4*)&xzbuf[0][s * G4 + j * 4] = xw;
            }
            __syncthreads();
        }
        const short* xzc = l2 ? &xzbuf[0][0] : &xzbuf[c & 1][0];

        // ---- 16 recurrent steps ----
#pragma unroll 2
        for (int s = 0; s < CHUNK; ++s) {
            const short* hb = &hA[s & 1][0];
            short8 af[4];
#pragma unroll
            for (int kc = 0; kc < 4; ++kc)
                af[kc] = *(const short8*)&hb[kc * 32 + quad * 8];

            ushort4 xq = *(const ushort4*)&xzc[s * G4 + j * 4];

            floatx4 acc[4];
#pragma unroll
            for (int g = 0; g < 4; ++g)
                acc[g] = __builtin_amdgcn_mfma_f32_16x16x32_bf16(af[0], bfrag[g][0], zero4, 0, 0, 0);
#pragma unroll
            for (int kc = 1; kc < 4; ++kc)
#pragma unroll
                for (int g = 0; g < 4; ++g)
                    acc[g] = __builtin_amdgcn_mfma_f32_16x16x32_bf16(af[kc], bfrag[g][kc], acc[g], 0, 0, 0);

            float zi = acc[0][0] + bf2f_(xq.x);
            float zf = acc[1][0] + bf2f_(xq.y);
            float zg = acc[2][0] + bf2f_(xq.z);
            float zo = acc[3][0] + bf2f_(xq.w);
            float ig = sigmoidf_(zi);
            float fg = sigmoidf_(zf);
            float gg = seluf_(zg);
            float og = sigmoidf_(zo);
            cst = fg * cst + ig * gg;
            float h = og * seluf_(cst);

            if (lane < 16) {                   // quad 0 publishes
                hA[(s + 1) & 1][j] = (short)f2bf_(h);
                hbuf[s * HID + j]  = h;
            }
            __syncthreads();
        }

        // ---- chunk boundary ----
        if (!l2) {
            // flush h chunk as bf16 + install prefetched xz chunk
            float4 hv = *(const float4*)&hbuf[tid * 4];
            ushort4 hw = make_ushort4(f2bf_(hv.x), f2bf_(hv.y), f2bf_(hv.z), f2bf_(hv.w));
            *(ushort4*)((char*)h1_b + ((size_t)c * CHUNK * HID + tid * 4) * 2) = hw;
            if (c + 1 < NCHUNK) {
                uint4* dst = (uint4*)&xzbuf[(c + 1) & 1][0];
                dst[tid] = pf0;
                dst[tid + 512] = pf1;
            }
            __syncthreads();   // per-wave vmcnt(0) drain: h1 stores complete (L2)
            if (tid == 0)      // release: wbl2 flushes this XCD's L2 -> memory
                __hip_atomic_store(&flags[b], (unsigned)(c + 1),
                                   __ATOMIC_RELEASE, __HIP_MEMORY_SCOPE_AGENT);
        } else {
            float4 hv = *(const float4*)&hbuf[tid * 4];
            *(float4*)&out_b[(size_t)c * CHUNK * HID + tid * 4] = hv;
            // next chunk's spin+syncthreads protects hbuf reuse
        }
    }
}

// ---------- host launch ----------
// ws layout (ws >= 192 MB proven by round-1's passing bf16 path):
//   [0, 128 MB)        xz1 bf16 (GEMM1 output)
//   [128 MB, 160 MB)   h1 bf16  (layer-1 -> layer-2 pipe)
//   [160 MB, +256 B)   per-row chunk flags (zeroed via memsetAsync each call)
extern "C" void kernel_launch(void* const* d_in, const int* in_sizes, int n_in,
                              void* d_out, int out_size, void* d_ws, size_t ws_size,
                              hipStream_t stream) {
    const float* x  = (const float*)d_in[0];
    const float* W1 = (const float*)d_in[1];
    const float* U1 = (const float*)d_in[2];
    const float* b1 = (const float*)d_in[3];
    const float* W2 = (const float*)d_in[4];
    const float* U2 = (const float*)d_in[5];
    const float* b2 = (const float*)d_in[6];
    float* out = (float*)d_out;

    const size_t BT        = (size_t)BATCH * SEQT;
    const size_t XZ1_BYTES = BT * G4 * 2;     // 128 MB
    const size_t H1_BYTES  = BT * HID * 2;    // 32 MB

    __hip_bfloat16* xzbuf = (__hip_bfloat16*)d_ws;
    __hip_bfloat16* h1g   = (__hip_bfloat16*)((char*)d_ws + XZ1_BYTES);
    unsigned*       flags = (unsigned*)((char*)d_ws + XZ1_BYTES + H1_BYTES);

    hipMemsetAsync(flags, 0, BATCH * sizeof(unsigned), stream);

    dim3 ggrid((unsigned)(BT / 32), 4), gblk(256);
    gemm_xw_bias<<<ggrid, gblk, 0, stream>>>(x, W1, b1, xzbuf, FEAT);

    fused_lstm<<<dim3(2 * BATCH), dim3(512), 0, stream>>>(
        xzbuf, U1, U2, W2, b2, h1g, flags, out);
}